// Round 1
// baseline (27.537 us; speedup 1.0000x reference)
//
#include <hip/hip_runtime.h>

#define HH 256
#define WW 256
#define SS 15
#define NB 64
#define EPSF 1e-6f

// Each block: one batch b, 1024 contiguous output pixels (256 threads x 4).
// Output [b][i][j] corresponds to canvas position (y=j, x=i)  (x-major
// positions flatten in the reference). 4 consecutive j share x -> dx^2
// computed once per sample.
__global__ __launch_bounds__(256) void CurveGraphic2d_kernel(
    const float* __restrict__ inputs,   // [64,4,2] normalized (y,x)
    const float* __restrict__ widths,   // [64]
    const float* __restrict__ aaf,      // [64]
    float* __restrict__ out)            // [64,256,256]
{
    const int blocksPerBatch = (HH * WW) / 1024;   // 64
    const int b     = blockIdx.x / blocksPerBatch;
    const int chunk = blockIdx.x % blocksPerBatch;
    const int tid   = threadIdx.x;

    __shared__ float spy[SS];
    __shared__ float spx[SS];

    if (tid < SS) {
        float t = (float)tid * (1.0f / (float)(SS - 1));
        float u = 1.0f - t;
        // K=4 cubic Bernstein basis
        float b0 = u * u * u;
        float b1 = 3.0f * t * u * u;
        float b2 = 3.0f * t * t * u;
        float b3 = t * t * t;
        const float* kp = inputs + b * 8;   // [4][2] = (y,x) pairs
        spy[tid] = 256.0f * (b0 * kp[0] + b1 * kp[2] + b2 * kp[4] + b3 * kp[6]);
        spx[tid] = 256.0f * (b0 * kp[1] + b1 * kp[3] + b2 * kp[5] + b3 * kp[7]);
    }
    __syncthreads();

    const float w  = widths[b];
    const float af = aaf[b];

    const int base = chunk * 1024 + tid * 4;       // offset within this image
    const int i = base >> 8;                        // row index  (= x coord)
    const int j = base & 255;                       // col index  (= y coord)
    const float x  = (float)i;
    const float y0 = (float)j;

    float m0 = 1e30f, m1 = 1e30f, m2 = 1e30f, m3 = 1e30f;
    #pragma unroll
    for (int s = 0; s < SS; ++s) {
        float dx  = x - spx[s];
        float dxx = dx * dx;
        float sy  = spy[s];
        float dy0 = y0          - sy;
        float dy1 = (y0 + 1.0f) - sy;
        float dy2 = (y0 + 2.0f) - sy;
        float dy3 = (y0 + 3.0f) - sy;
        m0 = fminf(m0, fmaf(dy0, dy0, dxx));
        m1 = fminf(m1, fmaf(dy1, dy1, dxx));
        m2 = fminf(m2, fmaf(dy2, dy2, dxx));
        m3 = fminf(m3, fmaf(dy3, dy3, dxx));
    }

    const float invw = 1.0f / w;
    float4 o;
    {
        float v = sqrtf(m0) * invw + EPSF;
        o.x = fminf(fmaxf(1.0f - __powf(v, af), 0.0f), 1.0f);
        v = sqrtf(m1) * invw + EPSF;
        o.y = fminf(fmaxf(1.0f - __powf(v, af), 0.0f), 1.0f);
        v = sqrtf(m2) * invw + EPSF;
        o.z = fminf(fmaxf(1.0f - __powf(v, af), 0.0f), 1.0f);
        v = sqrtf(m3) * invw + EPSF;
        o.w = fminf(fmaxf(1.0f - __powf(v, af), 0.0f), 1.0f);
    }

    *reinterpret_cast<float4*>(out + (size_t)b * (HH * WW) + base) = o;
}

extern "C" void kernel_launch(void* const* d_in, const int* in_sizes, int n_in,
                              void* d_out, int out_size, void* d_ws, size_t ws_size,
                              hipStream_t stream) {
    const float* inputs = (const float*)d_in[0];
    const float* widths = (const float*)d_in[1];
    const float* aaf    = (const float*)d_in[2];
    float* out = (float*)d_out;

    const int blocks = NB * ((HH * WW) / 1024);   // 64 * 64 = 4096
    CurveGraphic2d_kernel<<<blocks, 256, 0, stream>>>(inputs, widths, aaf, out);
}

// Round 2
// 12.645 us; speedup vs baseline: 2.1778x; 2.1778x over previous
//
#include <hip/hip_runtime.h>

#define HH 256
#define WW 256
#define SS 15
#define NB 64

// Single-instruction transcendentals (v_log_f32 = log2, v_exp_f32 = exp2).
__device__ __forceinline__ float alog2(float x) {
    float r; asm("v_log_f32 %0, %1" : "=v"(r) : "v"(x)); return r;
}
__device__ __forceinline__ float aexp2(float x) {
    float r; asm("v_exp_f32 %0, %1" : "=v"(r) : "v"(x)); return r;
}

// Each block: one batch b, 1024 contiguous output pixels (256 threads x 4).
// Output [b][i][j] corresponds to canvas position (y=j, x=i)  (x-major
// positions flatten in the reference). 4 consecutive j share x -> dx^2
// computed once per sample. Each wave covers exactly one x-column.
//
// Epilogue math:  (sqrt(m)/w + eps)^af  ->  exp2(0.5*af*log2(m) - af*log2(w))
// (eps dropped: worst-case deviation ~1.6e-3 << 2e-2 threshold; m=0 gives
//  log2(0) = -inf -> exp2 = 0 -> canvas 1, matching reference to ~1e-3.)
__global__ __launch_bounds__(256) void CurveGraphic2d_kernel(
    const float* __restrict__ inputs,   // [64,4,2] normalized (y,x)
    const float* __restrict__ widths,   // [64]
    const float* __restrict__ aaf,      // [64]
    float* __restrict__ out)            // [64,256,256]
{
    const int blocksPerBatch = (HH * WW) / 1024;   // 64
    const int b     = blockIdx.x / blocksPerBatch;
    const int chunk = blockIdx.x % blocksPerBatch;
    const int tid   = threadIdx.x;

    __shared__ float spy[SS];
    __shared__ float spx[SS];

    if (tid < SS) {
        float t = (float)tid * (1.0f / (float)(SS - 1));
        float u = 1.0f - t;
        // K=4 cubic Bernstein basis
        float b0 = u * u * u;
        float b1 = 3.0f * t * u * u;
        float b2 = 3.0f * t * t * u;
        float b3 = t * t * t;
        const float* kp = inputs + b * 8;   // [4][2] = (y,x) pairs
        spy[tid] = 256.0f * (b0 * kp[0] + b1 * kp[2] + b2 * kp[4] + b3 * kp[6]);
        spx[tid] = 256.0f * (b0 * kp[1] + b1 * kp[3] + b2 * kp[5] + b3 * kp[7]);
    }
    __syncthreads();

    const float w  = widths[b];
    const float af = aaf[b];
    const float haf   = 0.5f * af;           // 0.5*af  (sqrt folded into log)
    const float cbias = -af * log2f(w);      // -af*log2(w)

    const int base = chunk * 1024 + tid * 4;       // offset within this image
    const int i = base >> 8;                        // row index  (= x coord)
    const int j = base & 255;                       // col index  (= y coord)
    const float x  = (float)i;
    const float y0 = (float)j;

    float m0 = 1e30f, m1 = 1e30f, m2 = 1e30f, m3 = 1e30f;
    #pragma unroll
    for (int s = 0; s < SS; ++s) {
        float dx  = x - spx[s];
        float dxx = dx * dx;
        float sy  = spy[s];
        float dy0 = y0          - sy;
        float dy1 = (y0 + 1.0f) - sy;
        float dy2 = (y0 + 2.0f) - sy;
        float dy3 = (y0 + 3.0f) - sy;
        m0 = fminf(m0, fmaf(dy0, dy0, dxx));
        m1 = fminf(m1, fmaf(dy1, dy1, dxx));
        m2 = fminf(m2, fmaf(dy2, dy2, dxx));
        m3 = fminf(m3, fmaf(dy3, dy3, dxx));
    }

    float4 o;
    {
        float p;
        p   = aexp2(fmaf(haf, alog2(m0), cbias));
        o.x = fminf(fmaxf(1.0f - p, 0.0f), 1.0f);
        p   = aexp2(fmaf(haf, alog2(m1), cbias));
        o.y = fminf(fmaxf(1.0f - p, 0.0f), 1.0f);
        p   = aexp2(fmaf(haf, alog2(m2), cbias));
        o.z = fminf(fmaxf(1.0f - p, 0.0f), 1.0f);
        p   = aexp2(fmaf(haf, alog2(m3), cbias));
        o.w = fminf(fmaxf(1.0f - p, 0.0f), 1.0f);
    }

    *reinterpret_cast<float4*>(out + (size_t)b * (HH * WW) + base) = o;
}

extern "C" void kernel_launch(void* const* d_in, const int* in_sizes, int n_in,
                              void* d_out, int out_size, void* d_ws, size_t ws_size,
                              hipStream_t stream) {
    const float* inputs = (const float*)d_in[0];
    const float* widths = (const float*)d_in[1];
    const float* aaf    = (const float*)d_in[2];
    float* out = (float*)d_out;

    const int blocks = NB * ((HH * WW) / 1024);   // 64 * 64 = 4096
    CurveGraphic2d_kernel<<<blocks, 256, 0, stream>>>(inputs, widths, aaf, out);
}

// Round 3
// 11.285 us; speedup vs baseline: 2.4401x; 1.1205x over previous
//
#include <hip/hip_runtime.h>

#define HH 256
#define WW 256
#define SS 15
#define NB 64

// Single-instruction transcendentals (v_log_f32 = log2, v_exp_f32 = exp2).
__device__ __forceinline__ float alog2(float x) {
    float r; asm("v_log_f32 %0, %1" : "=v"(r) : "v"(x)); return r;
}
__device__ __forceinline__ float aexp2(float x) {
    float r; asm("v_exp_f32 %0, %1" : "=v"(r) : "v"(x)); return r;
}

// Each block: one batch b, 1024 contiguous output pixels (256 threads x 4).
// Output [b][i][j] corresponds to canvas position (y=j, x=i)  (x-major
// positions flatten in the reference). Each wave (64 lanes x 4 px) covers
// exactly one x-column -> dx is wave-uniform -> wave-uniform culling:
//   - output is exactly 0 when min_dist >= w  (clip of 1 - (d/w)^af)
//   - a sample with dx^2 >= w^2 can only contribute d >= w -> droppable
//   - if ALL samples have dx^2 >= w^2 -> whole column is 0 -> store zeros.
// Both culls are exact (computed min only grows, and both paths clamp to 0).
//
// Epilogue: (sqrt(m)/w + eps)^af -> exp2(0.5*af*log2(m) - af*log2(w))
// (eps dropped: worst-case deviation ~1.6e-3 << 2e-2 threshold.)
__global__ __launch_bounds__(256) void CurveGraphic2d_kernel(
    const float* __restrict__ inputs,   // [64,4,2] normalized (y,x)
    const float* __restrict__ widths,   // [64]
    const float* __restrict__ aaf,      // [64]
    float* __restrict__ out)            // [64,256,256]
{
    const int b     = blockIdx.x >> 6;        // 64 blocks per batch
    const int chunk = blockIdx.x & 63;
    const int tid   = threadIdx.x;

    __shared__ float spy[SS];
    __shared__ float spx[SS];

    if (tid < SS) {
        float t = (float)tid * (1.0f / (float)(SS - 1));
        float u = 1.0f - t;
        // K=4 cubic Bernstein basis
        float b0 = u * u * u;
        float b1 = 3.0f * t * u * u;
        float b2 = 3.0f * t * t * u;
        float b3 = t * t * t;
        const float* kp = inputs + b * 8;   // [4][2] = (y,x) pairs
        spy[tid] = 256.0f * (b0 * kp[0] + b1 * kp[2] + b2 * kp[4] + b3 * kp[6]);
        spx[tid] = 256.0f * (b0 * kp[1] + b1 * kp[3] + b2 * kp[5] + b3 * kp[7]);
    }
    __syncthreads();

    const float w  = widths[b];
    const float w2 = w * w;

    const int base = chunk * 1024 + tid * 4;       // offset within this image
    const int i = base >> 8;                        // row index  (= x coord)
    const int j = base & 255;                       // col index  (= y coord)
    const float x  = (float)i;
    const float y0 = (float)j;

    float* dst = out + (size_t)b * (HH * WW) + base;

    // --- cull pass: dx^2 per sample (wave-uniform values) ---
    float dxx[SS];
    float minv = 1e30f;
    #pragma unroll
    for (int s = 0; s < SS; ++s) {
        float dx = x - spx[s];
        dxx[s] = dx * dx;
        minv = fminf(minv, dxx[s]);
    }

    if (minv >= w2) {                 // whole column is zero (wave-uniform)
        *reinterpret_cast<float4*>(dst) = make_float4(0.f, 0.f, 0.f, 0.f);
        return;
    }

    // --- min-distance over surviving samples ---
    float m0 = 1e30f, m1 = 1e30f, m2 = 1e30f, m3 = 1e30f;
    #pragma unroll
    for (int s = 0; s < SS; ++s) {
        if (dxx[s] < w2) {            // wave-uniform branch
            float sy  = spy[s];
            float dy0 = y0          - sy;
            float dy1 = (y0 + 1.0f) - sy;
            float dy2 = (y0 + 2.0f) - sy;
            float dy3 = (y0 + 3.0f) - sy;
            m0 = fminf(m0, fmaf(dy0, dy0, dxx[s]));
            m1 = fminf(m1, fmaf(dy1, dy1, dxx[s]));
            m2 = fminf(m2, fmaf(dy2, dy2, dxx[s]));
            m3 = fminf(m3, fmaf(dy3, dy3, dxx[s]));
        }
    }

    const float af    = aaf[b];
    const float haf   = 0.5f * af;           // sqrt folded into the log
    const float cbias = -af * log2f(w);

    float4 o;
    float p;
    p   = aexp2(fmaf(haf, alog2(m0), cbias));
    o.x = fminf(fmaxf(1.0f - p, 0.0f), 1.0f);
    p   = aexp2(fmaf(haf, alog2(m1), cbias));
    o.y = fminf(fmaxf(1.0f - p, 0.0f), 1.0f);
    p   = aexp2(fmaf(haf, alog2(m2), cbias));
    o.z = fminf(fmaxf(1.0f - p, 0.0f), 1.0f);
    p   = aexp2(fmaf(haf, alog2(m3), cbias));
    o.w = fminf(fmaxf(1.0f - p, 0.0f), 1.0f);

    *reinterpret_cast<float4*>(dst) = o;
}

extern "C" void kernel_launch(void* const* d_in, const int* in_sizes, int n_in,
                              void* d_out, int out_size, void* d_ws, size_t ws_size,
                              hipStream_t stream) {
    const float* inputs = (const float*)d_in[0];
    const float* widths = (const float*)d_in[1];
    const float* aaf    = (const float*)d_in[2];
    float* out = (float*)d_out;

    const int blocks = NB * ((HH * WW) / 1024);   // 64 * 64 = 4096
    CurveGraphic2d_kernel<<<blocks, 256, 0, stream>>>(inputs, widths, aaf, out);
}